// Round 5
// baseline (41.180 us; speedup 1.0000x reference)
//
#include <hip/hip_runtime.h>

#define TPB 128
#define IPT 8          // source points per thread (contiguous)
#define NIB 4          // i-blocks: 4096 / (TPB*IPT)
#define NPTS 4096
#define NB 8
#define NJB 64
#define JCH (NPTS / NJB)   // 64 target points staged per block

typedef float v2f __attribute__((ext_vector_type(2)));

// packed f32 fma (VOP3P): d = a*b + c per 32-bit half
static __device__ __forceinline__ v2f pk_fma(v2f a, v2f b, v2f c) {
  v2f d;
  asm("v_pk_fma_f32 %0, %1, %2, %3" : "=v"(d) : "v"(a), "v"(b), "v"(c));
  return d;
}
// guaranteed 3-input min (compiler fusion of fminf-nests is not reliable w/o fast-math)
static __device__ __forceinline__ float min3f(float a, float b, float c) {
  float d;
  asm("v_min3_f32 %0, %1, %2, %3" : "=v"(d) : "v"(a), "v"(b), "v"(c));
  return d;
}

// Partial chamfer mins. grid = 2(dir)*NB*NIB*NJB = 4096 blocks (16/CU, 2-wave
// blocks, 5 waves/EU target). LDS pair-SoA per j-pair:
//   spr[2p]   = (x0,x1,y0,y1)
//   spr[2p+1] = (z0,z1,w0,w1), w = ||g||^2
// Inner: per j-pair per src pt: 3 v_pk_fma_f32 + 1 v_min3_f32.
__global__ __launch_bounds__(TPB, 5) void cd_partial_kernel(
    const float* __restrict__ pred, const float* __restrict__ gt,
    float* __restrict__ partial, float* __restrict__ out) {
  __shared__ float4 spr[JCH];

  if (blockIdx.x == 0 && threadIdx.x == 0) *out = 0.0f;

  int bid = blockIdx.x;
  int jb  = bid & (NJB - 1); bid >>= 6;
  int ib  = bid & (NIB - 1); bid >>= 2;
  int b   = bid & (NB - 1);  bid >>= 3;
  int dir = bid;  // 0: src=pred,tgt=gt ; 1: src=gt,tgt=pred

  const float* src = (dir == 0) ? pred : gt;
  const float* tgt = (dir == 0) ? gt : pred;
  src += (size_t)b * NPTS * 3;
  tgt += (size_t)b * NPTS * 3;

  const int t = threadIdx.x;
  const int ibase = ib * (TPB * IPT);

  // issue the 6 src float4 loads FIRST (latency hides under staging+barrier)
  const float4* sv = (const float4*)(src + (size_t)(ibase + t * IPT) * 3);
  float4 A = sv[0], B2 = sv[1], C = sv[2], D = sv[3], E = sv[4], F = sv[5];

  // stage target chunk into pair-SoA LDS (threads 0..JCH-1, one point each)
  if (t < JCH) {
    int jj = jb * JCH + t;
    float gx = tgt[jj * 3 + 0];
    float gy = tgt[jj * 3 + 1];
    float gz = tgt[jj * 3 + 2];
    float gw = fmaf(gx, gx, fmaf(gy, gy, gz * gz));
    int p = t >> 1, h = t & 1;
    float* base = (float*)&spr[2 * p];
    base[0 + h] = gx;
    base[2 + h] = gy;
    base[4 + h] = gz;
    base[6 + h] = gw;
  }

  float x[IPT], y[IPT], z[IPT];
  x[0]=A.x;  y[0]=A.y;  z[0]=A.z;
  x[1]=A.w;  y[1]=B2.x; z[1]=B2.y;
  x[2]=B2.z; y[2]=B2.w; z[2]=C.x;
  x[3]=C.y;  y[3]=C.z;  z[3]=C.w;
  x[4]=D.x;  y[4]=D.y;  z[4]=D.z;
  x[5]=D.w;  y[5]=E.x;  z[5]=E.y;
  x[6]=E.z;  y[6]=E.w;  z[6]=F.x;
  x[7]=F.y;  y[7]=F.z;  z[7]=F.w;

  v2f qx2[IPT], qy2[IPT], qz2[IPT];
  float pp[IPT], mn[IPT];
#pragma unroll
  for (int k = 0; k < IPT; ++k) {
    float qx = -2.0f * x[k], qy = -2.0f * y[k], qz = -2.0f * z[k];
    qx2[k] = (v2f){qx, qx};
    qy2[k] = (v2f){qy, qy};
    qz2[k] = (v2f){qz, qz};
    pp[k] = fmaf(x[k], x[k], fmaf(y[k], y[k], z[k] * z[k]));
    mn[k] = 3.4e38f;
  }
  __syncthreads();

  // main loop: per pair 2 broadcast ds_read_b128 + IPT*(3 pk_fma + 1 min3)
#pragma unroll 4
  for (int p = 0; p < JCH / 2; ++p) {
    float4 u = spr[2 * p];        // (x0,x1,y0,y1)
    float4 w = spr[2 * p + 1];    // (z0,z1,w0,w1)
    v2f X = (v2f){u.x, u.y};
    v2f Y = (v2f){u.z, u.w};
    v2f Z = (v2f){w.x, w.y};
    v2f W = (v2f){w.z, w.w};
#pragma unroll
    for (int k = 0; k < IPT; ++k) {
      v2f acc = pk_fma(qz2[k], Z, W);
      acc = pk_fma(qy2[k], Y, acc);
      acc = pk_fma(qx2[k], X, acc);
      mn[k] = min3f(mn[k], acc.x, acc.y);
    }
  }

  // vector store: 8 consecutive floats = 2 x float4
  float* outp = partial + ((size_t)((dir * NB + b) * NJB + jb)) * NPTS + ibase + t * IPT;
  float4 s0 = make_float4(mn[0] + pp[0], mn[1] + pp[1], mn[2] + pp[2], mn[3] + pp[3]);
  float4 s1 = make_float4(mn[4] + pp[4], mn[5] + pp[5], mn[6] + pp[6], mn[7] + pp[7]);
  ((float4*)outp)[0] = s0;
  ((float4*)outp)[1] = s1;
}

// Reduce: elementwise min over NJB j-chunks (float4 over i), sum, /NB.
// 16384 quads, one per thread; 64 independent coalesced float4 loads each.
__global__ __launch_bounds__(256) void cd_reduce_kernel(
    const float* __restrict__ partial, float* __restrict__ out) {
  const int quads = 2 * NB * NPTS / 4;  // 16384
  int tid = blockIdx.x * 256 + threadIdx.x;
  float local = 0.0f;
  for (int q = tid; q < quads; q += gridDim.x * 256) {
    int db = q >> 10;             // 1024 quads per (dir*NB+b)
    int i4 = (q & 1023) * 4;
    const float4* p = (const float4*)(partial + (size_t)db * NJB * NPTS + i4);
    float4 m = p[0];
#pragma unroll
    for (int jb = 1; jb < NJB; ++jb) {
      float4 v = p[(size_t)jb * (NPTS / 4)];
      m.x = fminf(m.x, v.x);
      m.y = fminf(m.y, v.y);
      m.z = fminf(m.z, v.z);
      m.w = fminf(m.w, v.w);
    }
    local += (m.x + m.y) + (m.z + m.w);
  }
  // wave reduce
#pragma unroll
  for (int off = 32; off > 0; off >>= 1) local += __shfl_down(local, off, 64);
  __shared__ float red[256 / 64];
  int wave = threadIdx.x >> 6;
  int lane = threadIdx.x & 63;
  if (lane == 0) red[wave] = local;
  __syncthreads();
  if (threadIdx.x == 0) {
    float s = 0.0f;
    for (int w = 0; w < 256 / 64; ++w) s += red[w];
    atomicAdd(out, s * (1.0f / NB));
  }
}

extern "C" void kernel_launch(void* const* d_in, const int* in_sizes, int n_in,
                              void* d_out, int out_size, void* d_ws, size_t ws_size,
                              hipStream_t stream) {
  const float* pred = (const float*)d_in[0];
  const float* gt   = (const float*)d_in[1];
  float* out        = (float*)d_out;
  float* partial    = (float*)d_ws;   // needs 2*NB*NJB*NPTS*4 = 16.8 MB << ws

  dim3 grid(2 * NB * NIB * NJB);      // 4096 blocks
  cd_partial_kernel<<<grid, TPB, 0, stream>>>(pred, gt, partial, out);
  cd_reduce_kernel<<<64, 256, 0, stream>>>(partial, out);
}